// Round 3
// baseline (166.344 us; speedup 1.0000x reference)
//
#include <hip/hip_runtime.h>

#define N_PTS 131072
#define DIM   128
#define KC    512
#define NT    2                 // n-tiles (of 16 points) per wave
#define WAVES 4
#define BLOCK (WAVES * 64)
#define PTS_PER_WG (WAVES * NT * 16)   // 128
#define KTILES (KC / 16)               // 32

typedef _Float16 half8 __attribute__((ext_vector_type(8)));
typedef float    f32x4 __attribute__((ext_vector_type(4)));

// ---------------- prep: centroids fp32 -> f16 hi/lo split + csq ----------------
__global__ __launch_bounds__(128)
void prep_centroids(const float* __restrict__ c,
                    _Float16* __restrict__ chi,
                    _Float16* __restrict__ clo,
                    float* __restrict__ csq) {
    const int k = blockIdx.x;
    const int d = threadIdx.x;
    float v = c[k * DIM + d];
    _Float16 hi = (_Float16)v;
    _Float16 lo = (_Float16)(v - (float)hi);
    chi[k * DIM + d] = hi;
    clo[k * DIM + d] = lo;

    float s = v * v;
    #pragma unroll
    for (int off = 1; off < 64; off <<= 1) s += __shfl_xor(s, off);
    __shared__ float red[2];
    if ((d & 63) == 0) red[d >> 6] = s;
    __syncthreads();
    if (d == 0) csq[k] = red[0] + red[1];
}

// ---------------- main: split-f16 MFMA + A-double-buffer + fused argmin ----------------
__global__ __launch_bounds__(BLOCK, 3)
void kmeans_mfma(const float* __restrict__ x,
                 const _Float16* __restrict__ chi,
                 const _Float16* __restrict__ clo,
                 const float* __restrict__ csq,
                 float* __restrict__ dist,
                 float* __restrict__ assign_out) {
    const int tid  = threadIdx.x;
    const int wave = tid >> 6;
    const int lane = tid & 63;
    const int col  = lane & 15;       // n within tile / k-row within A-tile
    const int g    = lane >> 4;       // lane group -> k-slot block (and C row group)
    const int n0   = blockIdx.x * PTS_PER_WG + wave * (NT * 16);

    // ---- B-frags: this wave's 32 points, hi/lo f16, resident in VGPRs ----
    half8 bhi[NT][4], blo[NT][4];
    float xsq[NT];
    #pragma unroll
    for (int t = 0; t < NT; ++t) {
        const float* xp = x + (size_t)(n0 + t * 16 + col) * DIM;
        float s = 0.f;
        #pragma unroll
        for (int sb = 0; sb < 4; ++sb) {
            const int dbase = sb * 32 + g * 8;
            float4 v0 = *(const float4*)(xp + dbase);
            float4 v1 = *(const float4*)(xp + dbase + 4);
            float vv[8] = {v0.x, v0.y, v0.z, v0.w, v1.x, v1.y, v1.z, v1.w};
            half8 h, l;
            #pragma unroll
            for (int j = 0; j < 8; ++j) {
                _Float16 hh = (_Float16)vv[j];
                h[j] = hh;
                l[j] = (_Float16)(vv[j] - (float)hh);
                s = fmaf(vv[j], vv[j], s);
            }
            bhi[t][sb] = h;
            blo[t][sb] = l;
        }
        s += __shfl_xor(s, 16);
        s += __shfl_xor(s, 32);
        xsq[t] = s;
    }

    float bestd[NT];
    int   bestk[NT];
    #pragma unroll
    for (int t = 0; t < NT; ++t) { bestd[t] = INFINITY; bestk[t] = 0; }

    // ---- A-frag register double buffer (static names -> no scratch, rule #20) ----
    half8 Ah0[4], Al0[4], Ah1[4], Al1[4];
    f32x4 cs0, cs1;

#define LOAD_A(KT, AH, AL, CS) do {                                          \
        const int krow_ = (KT) * 16 + col;                                   \
        const _Float16* ah_ = chi + (size_t)krow_ * DIM + g * 8;             \
        const _Float16* al_ = clo + (size_t)krow_ * DIM + g * 8;             \
        _Pragma("unroll")                                                    \
        for (int sb = 0; sb < 4; ++sb) {                                     \
            AH[sb] = *(const half8*)(ah_ + sb * 32);                         \
            AL[sb] = *(const half8*)(al_ + sb * 32);                         \
        }                                                                    \
        CS = *(const f32x4*)(csq + (KT) * 16 + g * 4);                       \
    } while (0)

#define COMPUTE(KT, AH, AL, CS) do {                                         \
        _Pragma("unroll")                                                    \
        for (int t = 0; t < NT; ++t) {                                       \
            f32x4 acc = {0.f, 0.f, 0.f, 0.f};                                \
            _Pragma("unroll")                                                \
            for (int sb = 0; sb < 4; ++sb) {                                 \
                acc = __builtin_amdgcn_mfma_f32_16x16x32_f16(AH[sb], bhi[t][sb], acc, 0, 0, 0); \
                acc = __builtin_amdgcn_mfma_f32_16x16x32_f16(AH[sb], blo[t][sb], acc, 0, 0, 0); \
                acc = __builtin_amdgcn_mfma_f32_16x16x32_f16(AL[sb], bhi[t][sb], acc, 0, 0, 0); \
            }                                                                \
            const int ncol = n0 + t * 16 + col;                              \
            _Pragma("unroll")                                                \
            for (int r = 0; r < 4; ++r) {                                    \
                const int kr = (KT) * 16 + g * 4 + r;                        \
                float dv = fmaf(-2.f, acc[r], xsq[t] + CS[r]);               \
                dist[(size_t)kr * N_PTS + ncol] = dv;                        \
                if (dv < bestd[t]) { bestd[t] = dv; bestk[t] = kr; }         \
            }                                                                \
        }                                                                    \
    } while (0)

    LOAD_A(0, Ah0, Al0, cs0);
    for (int kt = 0; kt < KTILES; kt += 2) {
        // prefetch next A BEFORE this tile's stores -> waiting on A never drains stores
        LOAD_A(kt + 1, Ah1, Al1, cs1);
        COMPUTE(kt, Ah0, Al0, cs0);
        if (kt + 2 < KTILES) LOAD_A(kt + 2, Ah0, Al0, cs0);
        COMPUTE(kt + 1, Ah1, Al1, cs1);
    }

    // ---- cross-lane argmin over the 4 lane groups ----
    #pragma unroll
    for (int t = 0; t < NT; ++t) {
        float d = bestd[t];
        int   k = bestk[t];
        #pragma unroll
        for (int off = 16; off < 64; off <<= 1) {
            float od = __shfl_xor(d, off);
            int   ok = __shfl_xor(k, off);
            if (od < d || (od == d && ok < k)) { d = od; k = ok; }
        }
        if (g == 0) assign_out[n0 + t * 16 + col] = (float)k;
    }
}

extern "C" void kernel_launch(void* const* d_in, const int* in_sizes, int n_in,
                              void* d_out, int out_size, void* d_ws, size_t ws_size,
                              hipStream_t stream) {
    const float* x = (const float*)d_in[0];   // [N, D]
    const float* c = (const float*)d_in[1];   // [K, D]
    float* dist       = (float*)d_out;                 // [K, N]
    float* assign_out = dist + (size_t)KC * N_PTS;     // [N] as float

    _Float16* chi = (_Float16*)d_ws;
    _Float16* clo = chi + (size_t)KC * DIM;
    float*    csq = (float*)(clo + (size_t)KC * DIM);

    prep_centroids<<<KC, DIM, 0, stream>>>(c, chi, clo, csq);
    kmeans_mfma<<<N_PTS / PTS_PER_WG, BLOCK, 0, stream>>>(x, chi, clo, csq, dist, assign_out);
}

// Round 4
// 108.770 us; speedup vs baseline: 1.5293x; 1.5293x over previous
//
#include <hip/hip_runtime.h>

#define N_PTS 131072
#define DIM   128
#define KC    512
#define NT    4                 // n-tiles (of 16 points) per wave
#define WAVES 4
#define BLOCK (WAVES * 64)
#define PTS_PER_WG (WAVES * NT * 16)   // 256
#define KTILES (KC / 16)               // 32

typedef _Float16 half8 __attribute__((ext_vector_type(8)));
typedef float    f32x4 __attribute__((ext_vector_type(4)));

#define SCHED_FENCE() __builtin_amdgcn_sched_barrier(0)

// ---------------- prep: centroids fp32 -> f16 hi/lo split + csq ----------------
__global__ __launch_bounds__(128)
void prep_centroids(const float* __restrict__ c,
                    _Float16* __restrict__ chi,
                    _Float16* __restrict__ clo,
                    float* __restrict__ csq) {
    const int k = blockIdx.x;
    const int d = threadIdx.x;
    float v = c[k * DIM + d];
    _Float16 hi = (_Float16)v;
    _Float16 lo = (_Float16)(v - (float)hi);
    chi[k * DIM + d] = hi;
    clo[k * DIM + d] = lo;

    float s = v * v;
    #pragma unroll
    for (int off = 1; off < 64; off <<= 1) s += __shfl_xor(s, off);
    __shared__ float red[2];
    if ((d & 63) == 0) red[d >> 6] = s;
    __syncthreads();
    if (d == 0) csq[k] = red[0] + red[1];
}

// ---------------- main: split-f16 MFMA, pinned A-prefetch, fused argmin ----------------
__global__ __launch_bounds__(BLOCK, 2)
void kmeans_mfma(const float* __restrict__ x,
                 const _Float16* __restrict__ chi,
                 const _Float16* __restrict__ clo,
                 const float* __restrict__ csq,
                 float* __restrict__ dist,
                 float* __restrict__ assign_out) {
    const int tid  = threadIdx.x;
    const int wave = tid >> 6;
    const int lane = tid & 63;
    const int col  = lane & 15;       // n within tile / k-row within A-tile
    const int g    = lane >> 4;       // lane group -> k-slot block (and C row group)
    const int n0   = blockIdx.x * PTS_PER_WG + wave * (NT * 16);

    // ---- B-frags: this wave's 64 points, hi/lo f16, resident in VGPRs ----
    half8 bhi[NT][4], blo[NT][4];
    float xsq[NT];
    #pragma unroll
    for (int t = 0; t < NT; ++t) {
        const float* xp = x + (size_t)(n0 + t * 16 + col) * DIM;
        float s = 0.f;
        #pragma unroll
        for (int sb = 0; sb < 4; ++sb) {
            const int dbase = sb * 32 + g * 8;
            float4 v0 = *(const float4*)(xp + dbase);
            float4 v1 = *(const float4*)(xp + dbase + 4);
            float vv[8] = {v0.x, v0.y, v0.z, v0.w, v1.x, v1.y, v1.z, v1.w};
            half8 h, l;
            #pragma unroll
            for (int j = 0; j < 8; ++j) {
                _Float16 hh = (_Float16)vv[j];
                h[j] = hh;
                l[j] = (_Float16)(vv[j] - (float)hh);
                s = fmaf(vv[j], vv[j], s);
            }
            bhi[t][sb] = h;
            blo[t][sb] = l;
        }
        s += __shfl_xor(s, 16);
        s += __shfl_xor(s, 32);
        xsq[t] = s;
    }

    float bestd[NT];
    int   bestk[NT];
    #pragma unroll
    for (int t = 0; t < NT; ++t) { bestd[t] = INFINITY; bestk[t] = 0; }

    // ---- A-frag register double buffer (static names; pinned by sched fences) ----
    half8 Ah0[4], Al0[4], Ah1[4], Al1[4];
    f32x4 cs0, cs1;

#define LOAD_A(KT, AH, AL, CS) do {                                          \
        const int krow_ = (KT) * 16 + col;                                   \
        const _Float16* ah_ = chi + (size_t)krow_ * DIM + g * 8;             \
        const _Float16* al_ = clo + (size_t)krow_ * DIM + g * 8;             \
        _Pragma("unroll")                                                    \
        for (int sb = 0; sb < 4; ++sb) {                                     \
            AH[sb] = *(const half8*)(ah_ + sb * 32);                         \
            AL[sb] = *(const half8*)(al_ + sb * 32);                         \
        }                                                                    \
        CS = *(const f32x4*)(csq + (KT) * 16 + g * 4);                       \
    } while (0)

    // compute all NT acc tiles, then store r-outer/t-inner (4 consecutive insts
    // cover 256B contiguous per k-row -> L2 can merge into full lines)
#define COMPUTE(KT, AH, AL, CS) do {                                         \
        f32x4 acc_[NT];                                                      \
        _Pragma("unroll")                                                    \
        for (int t = 0; t < NT; ++t) {                                       \
            f32x4 a_ = {0.f, 0.f, 0.f, 0.f};                                 \
            _Pragma("unroll")                                                \
            for (int sb = 0; sb < 4; ++sb) {                                 \
                a_ = __builtin_amdgcn_mfma_f32_16x16x32_f16(AH[sb], bhi[t][sb], a_, 0, 0, 0); \
                a_ = __builtin_amdgcn_mfma_f32_16x16x32_f16(AH[sb], blo[t][sb], a_, 0, 0, 0); \
                a_ = __builtin_amdgcn_mfma_f32_16x16x32_f16(AL[sb], bhi[t][sb], a_, 0, 0, 0); \
            }                                                                \
            acc_[t] = a_;                                                    \
        }                                                                    \
        _Pragma("unroll")                                                    \
        for (int r = 0; r < 4; ++r) {                                        \
            const int kr = (KT) * 16 + g * 4 + r;                            \
            float* drow = dist + (size_t)kr * N_PTS + n0 + col;              \
            _Pragma("unroll")                                                \
            for (int t = 0; t < NT; ++t) {                                   \
                float dv = fmaf(-2.f, acc_[t][r], xsq[t] + CS[r]);           \
                drow[t * 16] = dv;                                           \
                if (dv < bestd[t]) { bestd[t] = dv; bestk[t] = kr; }         \
            }                                                                \
        }                                                                    \
    } while (0)

    LOAD_A(0, Ah0, Al0, cs0);
    for (int kt = 0; kt < KTILES; kt += 2) {
        LOAD_A(kt + 1, Ah1, Al1, cs1);   // issued BEFORE kt's stores
        SCHED_FENCE();                   // loads can't sink, stores can't hoist
        COMPUTE(kt, Ah0, Al0, cs0);
        if (kt + 2 < KTILES) LOAD_A(kt + 2, Ah0, Al0, cs0);
        SCHED_FENCE();
        COMPUTE(kt + 1, Ah1, Al1, cs1);
    }

    // ---- cross-lane argmin over the 4 lane groups ----
    #pragma unroll
    for (int t = 0; t < NT; ++t) {
        float d = bestd[t];
        int   k = bestk[t];
        #pragma unroll
        for (int off = 16; off < 64; off <<= 1) {
            float od = __shfl_xor(d, off);
            int   ok = __shfl_xor(k, off);
            if (od < d || (od == d && ok < k)) { d = od; k = ok; }
        }
        if (g == 0) assign_out[n0 + t * 16 + col] = (float)k;
    }
}

extern "C" void kernel_launch(void* const* d_in, const int* in_sizes, int n_in,
                              void* d_out, int out_size, void* d_ws, size_t ws_size,
                              hipStream_t stream) {
    const float* x = (const float*)d_in[0];   // [N, D]
    const float* c = (const float*)d_in[1];   // [K, D]
    float* dist       = (float*)d_out;                 // [K, N]
    float* assign_out = dist + (size_t)KC * N_PTS;     // [N] as float

    _Float16* chi = (_Float16*)d_ws;
    _Float16* clo = chi + (size_t)KC * DIM;
    float*    csq = (float*)(clo + (size_t)KC * DIM);

    prep_centroids<<<KC, DIM, 0, stream>>>(c, chi, clo, csq);
    kmeans_mfma<<<N_PTS / PTS_PER_WG, BLOCK, 0, stream>>>(x, chi, clo, csq, dist, assign_out);
}

// Round 5
// 85.523 us; speedup vs baseline: 1.9450x; 1.2718x over previous
//
#include <hip/hip_runtime.h>

#define N_PTS 131072
#define DIM   128
#define KC    512
#define NT    4                 // n-tiles (of 16 points) per wave
#define WAVES 4
#define BLOCK (WAVES * 64)
#define PTS_PER_WG (WAVES * NT * 16)   // 256
#define KTILES (KC / 16)               // 32
#define TILE_BYTES 8192                // hi 4KB + lo 4KB per k-tile (swizzled)

typedef _Float16 half8 __attribute__((ext_vector_type(8)));
typedef float    f32x4 __attribute__((ext_vector_type(4)));

// ---------------- prep: centroids fp32 -> swizzled f16 hi/lo tiles + csq --------
// ws tile layout: tile kt = [hi 4KB | lo 4KB]; within each: row r (=k&15) at
// r*256, byte b(dim d)=2d stored at b ^ ((r&7)<<4)  (XOR swizzle, 16B-granular)
__global__ __launch_bounds__(128)
void prep_centroids(const float* __restrict__ c,
                    unsigned char* __restrict__ tiles,
                    float* __restrict__ csq) {
    const int k = blockIdx.x;
    const int d = threadIdx.x;
    float v = c[k * DIM + d];
    _Float16 hi = (_Float16)v;
    _Float16 lo = (_Float16)(v - (float)hi);

    const int kt = k >> 4, row = k & 15;
    const unsigned bsw = (unsigned)(2 * d) ^ (unsigned)((row & 7) << 4);
    unsigned char* tb = tiles + (size_t)kt * TILE_BYTES + row * 256 + bsw;
    *(_Float16*)(tb)        = hi;
    *(_Float16*)(tb + 4096) = lo;

    float s = v * v;
    #pragma unroll
    for (int off = 1; off < 64; off <<= 1) s += __shfl_xor(s, off);
    __shared__ float red[2];
    if ((d & 63) == 0) red[d >> 6] = s;
    __syncthreads();
    if (d == 0) csq[k] = red[0] + red[1];
}

// async global->LDS, 16B per lane; LDS dest = wave-uniform base (+lane*16 by HW)
__device__ __forceinline__ void stage16(const void* g, void* l) {
    __builtin_amdgcn_global_load_lds(
        (const __attribute__((address_space(1))) void*)g,
        (__attribute__((address_space(3))) void*)l, 16, 0, 0);
}

// ---------------- main: LDS-staged A (dbuf, counted vmcnt), fused argmin --------
__global__ __launch_bounds__(BLOCK, 2)
void kmeans_mfma(const float* __restrict__ x,
                 const unsigned char* __restrict__ tiles,
                 const float* __restrict__ csq,
                 float* __restrict__ dist,
                 float* __restrict__ assign_out) {
    __shared__ alignas(16) unsigned char abuf[2 * TILE_BYTES];
    __shared__ alignas(16) float csq_lds[KC];

    const int tid  = threadIdx.x;
    const int wave = tid >> 6;
    const int lane = tid & 63;
    const int col  = lane & 15;       // n within tile / A row within k-tile
    const int g    = lane >> 4;       // lane group -> k-slot block / C row group
    const int n0   = blockIdx.x * PTS_PER_WG + wave * (NT * 16);

    // ---- stage tile 0 (each wave copies its 2KB slice) ----
    {
        const unsigned char* src = tiles + (size_t)(wave * 2) * 1024 + lane * 16;
        unsigned char* dst = abuf + (wave * 2) * 1024;
        stage16(src, dst);
        stage16(src + 1024, dst + 1024);
    }

    // ---- csq -> LDS (removes VMEM loads from the k-loop) ----
    csq_lds[tid]       = csq[tid];
    csq_lds[tid + 256] = csq[tid + 256];

    // ---- B-frags: this wave's 64 points, hi/lo f16, resident in VGPRs ----
    half8 bhi[NT][4], blo[NT][4];
    float xsq[NT];
    #pragma unroll
    for (int t = 0; t < NT; ++t) {
        const float* xp = x + (size_t)(n0 + t * 16 + col) * DIM;
        float s = 0.f;
        #pragma unroll
        for (int sb = 0; sb < 4; ++sb) {
            const int dbase = sb * 32 + g * 8;
            float4 v0 = *(const float4*)(xp + dbase);
            float4 v1 = *(const float4*)(xp + dbase + 4);
            float vv[8] = {v0.x, v0.y, v0.z, v0.w, v1.x, v1.y, v1.z, v1.w};
            half8 h, l;
            #pragma unroll
            for (int j = 0; j < 8; ++j) {
                _Float16 hh = (_Float16)vv[j];
                h[j] = hh;
                l[j] = (_Float16)(vv[j] - (float)hh);
                s = fmaf(vv[j], vv[j], s);
            }
            bhi[t][sb] = h;
            blo[t][sb] = l;
        }
        s += __shfl_xor(s, 16);
        s += __shfl_xor(s, 32);
        xsq[t] = s;
    }

    float bestd[NT];
    int   bestk[NT];
    #pragma unroll
    for (int t = 0; t < NT; ++t) { bestd[t] = INFINITY; bestk[t] = 0; }

    __syncthreads();   // full drain: tile-0 stage + csq ds_writes complete

    int cur = 0;
    for (int kt = 0; kt < KTILES; ++kt) {
        // ---- issue next tile's stage FIRST (hides under MFMA+stores) ----
        if (kt + 1 < KTILES) {
            const unsigned char* src = tiles + (size_t)(kt + 1) * TILE_BYTES
                                     + (wave * 2) * 1024 + lane * 16;
            unsigned char* dst = abuf + (cur ^ 1) * TILE_BYTES + (wave * 2) * 1024;
            stage16(src, dst);
            stage16(src + 1024, dst + 1024);
        }
        __builtin_amdgcn_sched_barrier(0);

        // ---- A-frags from LDS (swizzled read matches prep's layout) ----
        const unsigned char* buf = abuf + cur * TILE_BYTES;
        half8 Ah[4], Al[4];
        #pragma unroll
        for (int sb = 0; sb < 4; ++sb) {
            const unsigned b = (unsigned)((sb * 64 + g * 16) ^ ((col & 7) << 4));
            Ah[sb] = *(const half8*)(buf + col * 256 + b);
            Al[sb] = *(const half8*)(buf + 4096 + col * 256 + b);
        }
        f32x4 cs4 = *(const f32x4*)(&csq_lds[kt * 16 + g * 4]);

        // ---- MFMA: 3-pass split-f16, NT independent chains ----
        f32x4 acc[NT];
        #pragma unroll
        for (int t = 0; t < NT; ++t) {
            f32x4 a_ = {0.f, 0.f, 0.f, 0.f};
            #pragma unroll
            for (int sb = 0; sb < 4; ++sb) {
                a_ = __builtin_amdgcn_mfma_f32_16x16x32_f16(Ah[sb], bhi[t][sb], a_, 0, 0, 0);
                a_ = __builtin_amdgcn_mfma_f32_16x16x32_f16(Ah[sb], blo[t][sb], a_, 0, 0, 0);
                a_ = __builtin_amdgcn_mfma_f32_16x16x32_f16(Al[sb], bhi[t][sb], a_, 0, 0, 0);
            }
            acc[t] = a_;
        }

        // ---- epilogue: r-outer/t-inner stores (256B/row contiguous) + argmin ----
        #pragma unroll
        for (int r = 0; r < 4; ++r) {
            const int kr = kt * 16 + g * 4 + r;
            float* drow = dist + (size_t)kr * N_PTS + n0 + col;
            #pragma unroll
            for (int t = 0; t < NT; ++t) {
                float dv = fmaf(-2.f, acc[t][r], xsq[t] + cs4[r]);
                drow[t * 16] = dv;
                if (dv < bestd[t]) { bestd[t] = dv; bestk[t] = kr; }
            }
        }

        // ---- counted wait: 18 VMEM outstanding (2 stage + 16 stores);
        //      vmcnt(16) retires the stage, never drains this tile's stores ----
        if (kt + 1 < KTILES) {
            asm volatile("s_waitcnt vmcnt(16)" ::: "memory");
            __builtin_amdgcn_sched_barrier(0);
            __builtin_amdgcn_s_barrier();
            cur ^= 1;
        }
    }

    // ---- cross-lane argmin over the 4 lane groups ----
    #pragma unroll
    for (int t = 0; t < NT; ++t) {
        float d = bestd[t];
        int   k = bestk[t];
        #pragma unroll
        for (int off = 16; off < 64; off <<= 1) {
            float od = __shfl_xor(d, off);
            int   ok = __shfl_xor(k, off);
            if (od < d || (od == d && ok < k)) { d = od; k = ok; }
        }
        if (g == 0) assign_out[n0 + t * 16 + col] = (float)k;
    }
}

extern "C" void kernel_launch(void* const* d_in, const int* in_sizes, int n_in,
                              void* d_out, int out_size, void* d_ws, size_t ws_size,
                              hipStream_t stream) {
    const float* x = (const float*)d_in[0];   // [N, D]
    const float* c = (const float*)d_in[1];   // [K, D]
    float* dist       = (float*)d_out;                 // [K, N]
    float* assign_out = dist + (size_t)KC * N_PTS;     // [N] as float

    // ws: swizzled tiles [32 * 8KB = 256KB] | csq f32[512]
    unsigned char* tiles = (unsigned char*)d_ws;
    float* csq = (float*)(tiles + (size_t)KTILES * TILE_BYTES);

    prep_centroids<<<KC, DIM, 0, stream>>>(c, tiles, csq);
    kmeans_mfma<<<N_PTS / PTS_PER_WG, BLOCK, 0, stream>>>(x, tiles, csq, dist, assign_out);
}